// Round 5
// baseline (89.189 us; speedup 1.0000x reference)
//
#include <hip/hip_runtime.h>

#define H   384
#define W   1280
#define PH  192
#define PW  640
#define PP  (PH*PW)      // 122880 pixels per pooled plane

typedef float f32x4 __attribute__((ext_vector_type(4)));
typedef int   i32x4 __attribute__((ext_vector_type(4)));

// ---------------------------------------------------------------------------
// Kernel A: 2x2 average pool + RGB->YCbCr for both images, both batches.
// Explicit round-to-nearest intrinsics in numpy evaluation order so the
// census '>=' comparisons match the reference bit-for-bit.
// ---------------------------------------------------------------------------
__global__ __launch_bounds__(256) void pool_ycbcr_kernel(
    const float* __restrict__ left, const float* __restrict__ right,
    float* __restrict__ yp, float* __restrict__ cbp, float* __restrict__ crp)
{
    int tid = blockIdx.x * blockDim.x + threadIdx.x;
    if (tid >= 4 * PP) return;
    int p   = tid / PP;
    int rem = tid - p * PP;
    int y   = rem / PW;
    int x   = rem - y * PW;

    const float* src = (p < 2 ? left : right) + (size_t)(p & 1) * 3 * H * W;

    float pc[3];
#pragma unroll
    for (int c = 0; c < 3; ++c) {
        const float* ch = src + (size_t)c * H * W + (size_t)(2 * y) * W + 2 * x;
        float2 a = *(const float2*)ch;
        float2 b = *(const float2*)(ch + W);
        float s = __fadd_rn(__fadd_rn(__fadd_rn(a.x, a.y), b.x), b.y);
        pc[c] = __fmul_rn(s, 0.25f);
    }
    float yv = __fadd_rn(__fadd_rn(__fmul_rn(0.299f, pc[0]),
                                   __fmul_rn(0.587f, pc[1])),
                         __fmul_rn(0.114f, pc[2]));
    float cb = __fadd_rn(__fmul_rn(__fsub_rn(pc[2], yv), 0.564f), 0.5f);
    float cr = __fadd_rn(__fmul_rn(__fsub_rn(pc[0], yv), 0.713f), 0.5f);

    yp[tid]  = yv;
    cbp[tid] = cb;
    crp[tid] = cr;
}

// ---------------------------------------------------------------------------
// Kernel B: 5x5 census transform (24 bits, MSB = offset (0,0)), zero border.
// ---------------------------------------------------------------------------
__global__ __launch_bounds__(256) void census_kernel(
    const float* __restrict__ yp, int* __restrict__ cen)
{
    int tid = blockIdx.x * blockDim.x + threadIdx.x;
    if (tid >= 4 * PP) return;
    int p   = tid / PP;
    int rem = tid - p * PP;
    int y   = rem / PW;
    int x   = rem - y * PW;

    int code = 0;
    if (y >= 2 && y < PH - 2 && x >= 2 && x < PW - 2) {
        const float* base = yp + (size_t)p * PP;
        float c = base[y * PW + x];
        int bit = 23;
#pragma unroll
        for (int v = 0; v < 5; ++v) {
#pragma unroll
            for (int u = 0; u < 5; ++u) {
                if (u == 2 && v == 2) continue;  // center excluded
                float nb = base[(y - 2 + v) * PW + (x - 2 + u)];
                code |= (nb >= c ? 1 : 0) << bit;
                --bit;
            }
        }
    }
    cen[tid] = code;
}

// ---------------------------------------------------------------------------
// Kernel C: cost volume + normalization.
// Block = (n, g, row, d-half): stage L/R rows in LDS ONCE, then emit all 64
// disparities for that row from LDS. Global reads drop 128x (754MB L2
// traffic -> ~12MB); stores (the 377MB floor) are NT float4.
// Garbage in the unstaged LDS pad / masked region is never selected.
// ---------------------------------------------------------------------------
__global__ __launch_bounds__(256) void costvol_kernel(
    const float* __restrict__ cbp, const float* __restrict__ crp,
    const int* __restrict__ cen, float* __restrict__ out)
{
    const float m1 = 11.08282948f, i1 = 1.0f / 0.1949711f;
    const float m2 = 0.02175535f,  i2 = 1.0f / 35.91432953f;
    const float m3 = 0.02679042f,  i3 = 1.0f / 26.79782867f;

    int b   = blockIdx.x;           // 2304 blocks
    int n   = b / 1152;
    int r   = b - n * 1152;
    int g   = r / 384;              // block-uniform
    int r2  = r - g * 384;
    int row = r2 >> 1;
    int dh  = r2 & 1;               // d-half: d = dh*64 + dd

    __shared__ int Ls[776];         // 640 staged + pad for d-overread
    __shared__ int Rs[640];

    const int* Lplane;
    const int* Rplane;
    if (g == 0)      { Lplane = cen + (size_t)n * PP;
                       Rplane = cen + (size_t)(2 + n) * PP; }
    else if (g == 1) { Lplane = (const int*)(cbp + (size_t)n * PP);
                       Rplane = (const int*)(cbp + (size_t)(2 + n) * PP); }
    else             { Lplane = (const int*)(crp + (size_t)n * PP);
                       Rplane = (const int*)(crp + (size_t)(2 + n) * PP); }

    const i32x4* Lg4 = (const i32x4*)(Lplane + row * PW);
    const i32x4* Rg4 = (const i32x4*)(Rplane + row * PW);

    const int t = threadIdx.x;
    for (int j = t; j < 320; j += 256) {
        if (j < 160) *(i32x4*)&Ls[j * 4]         = Lg4[j];
        else         *(i32x4*)&Rs[(j - 160) * 4] = Rg4[j - 160];
    }
    __syncthreads();

    float* outb = out + ((size_t)(n * 384 + g * 128 + dh * 64) * PH + row) * PW;

    if (g == 0) {
        const float c0 = (0.0f - m1) * i1;
#pragma unroll 4
        for (int idx = t; idx < 64 * 160; idx += 256) {
            int dd = idx / 160;            // 0..63
            int q  = idx - dd * 160;
            int x0 = q * 4;
            int d  = dh * 64 + dd;
            int nvalid = PW - d;
            i32x4 rv = *(const i32x4*)&Rs[x0];
            int base = x0 + d;
            int e0 = Ls[base], e1 = Ls[base + 1], e2 = Ls[base + 2], e3 = Ls[base + 3];
            f32x4 ov;
            ov.x = (x0 + 0 < nvalid) ? ((float)__popc(e0 ^ rv.x) - m1) * i1 : c0;
            ov.y = (x0 + 1 < nvalid) ? ((float)__popc(e1 ^ rv.y) - m1) * i1 : c0;
            ov.z = (x0 + 2 < nvalid) ? ((float)__popc(e2 ^ rv.z) - m1) * i1 : c0;
            ov.w = (x0 + 3 < nvalid) ? ((float)__popc(e3 ^ rv.w) - m1) * i1 : c0;
            __builtin_nontemporal_store(ov, (f32x4*)(outb + (size_t)dd * PP + x0));
        }
    } else {
        const float m  = (g == 1) ? m2 : m3;
        const float iv = (g == 1) ? i2 : i3;
        const float c0 = (0.0f - m) * iv;
        const float* Lf = (const float*)Ls;
        const float* Rf = (const float*)Rs;
#pragma unroll 4
        for (int idx = t; idx < 64 * 160; idx += 256) {
            int dd = idx / 160;
            int q  = idx - dd * 160;
            int x0 = q * 4;
            int d  = dh * 64 + dd;
            int nvalid = PW - d;
            f32x4 rv = *(const f32x4*)&Rf[x0];
            int base = x0 + d;
            float e0 = Lf[base], e1 = Lf[base + 1], e2 = Lf[base + 2], e3 = Lf[base + 3];
            f32x4 ov;
            ov.x = (x0 + 0 < nvalid) ? (fabsf(e0 - rv.x) - m) * iv : c0;
            ov.y = (x0 + 1 < nvalid) ? (fabsf(e1 - rv.y) - m) * iv : c0;
            ov.z = (x0 + 2 < nvalid) ? (fabsf(e2 - rv.z) - m) * iv : c0;
            ov.w = (x0 + 3 < nvalid) ? (fabsf(e3 - rv.w) - m) * iv : c0;
            __builtin_nontemporal_store(ov, (f32x4*)(outb + (size_t)dd * PP + x0));
        }
    }
}

// ---------------------------------------------------------------------------
extern "C" void kernel_launch(void* const* d_in, const int* in_sizes, int n_in,
                              void* d_out, int out_size, void* d_ws, size_t ws_size,
                              hipStream_t stream)
{
    const float* left  = (const float*)d_in[0];
    const float* right = (const float*)d_in[1];

    float* ws  = (float*)d_ws;
    float* yp  = ws;                     // 4 planes of PP floats
    float* cbp = ws + 4 * PP;
    float* crp = ws + 8 * PP;
    int*   cen = (int*)(ws + 12 * PP);   // 4 planes of PP int32

    int threads = 256;
    int blocksAB = (4 * PP + threads - 1) / threads;   // 1920

    pool_ycbcr_kernel<<<blocksAB, threads, 0, stream>>>(left, right, yp, cbp, crp);
    census_kernel<<<blocksAB, threads, 0, stream>>>(yp, cen);

    int blocksC = 2 * 3 * 192 * 2;   // 2304: (n, g, row, d-half)
    costvol_kernel<<<blocksC, threads, 0, stream>>>(cbp, crp, cen, (float*)d_out);
}

// Round 6
// 87.573 us; speedup vs baseline: 1.0184x; 1.0184x over previous
//
#include <hip/hip_runtime.h>

#define H   384
#define W   1280
#define PH  192
#define PW  640
#define PP  (PH*PW)      // 122880 pixels per pooled plane

typedef float f32x4 __attribute__((ext_vector_type(4)));
typedef int   i32x4 __attribute__((ext_vector_type(4)));

// ---------------------------------------------------------------------------
// Kernel A: 2x2 average pool + RGB->YCbCr for both images, both batches.
// Explicit round-to-nearest intrinsics in numpy evaluation order so the
// census '>=' comparisons match the reference bit-for-bit.
// ---------------------------------------------------------------------------
__global__ __launch_bounds__(256) void pool_ycbcr_kernel(
    const float* __restrict__ left, const float* __restrict__ right,
    float* __restrict__ yp, float* __restrict__ cbp, float* __restrict__ crp)
{
    int tid = blockIdx.x * blockDim.x + threadIdx.x;
    if (tid >= 4 * PP) return;
    int p   = tid / PP;
    int rem = tid - p * PP;
    int y   = rem / PW;
    int x   = rem - y * PW;

    const float* src = (p < 2 ? left : right) + (size_t)(p & 1) * 3 * H * W;

    float pc[3];
#pragma unroll
    for (int c = 0; c < 3; ++c) {
        const float* ch = src + (size_t)c * H * W + (size_t)(2 * y) * W + 2 * x;
        float2 a = *(const float2*)ch;
        float2 b = *(const float2*)(ch + W);
        float s = __fadd_rn(__fadd_rn(__fadd_rn(a.x, a.y), b.x), b.y);
        pc[c] = __fmul_rn(s, 0.25f);
    }
    float yv = __fadd_rn(__fadd_rn(__fmul_rn(0.299f, pc[0]),
                                   __fmul_rn(0.587f, pc[1])),
                         __fmul_rn(0.114f, pc[2]));
    float cb = __fadd_rn(__fmul_rn(__fsub_rn(pc[2], yv), 0.564f), 0.5f);
    float cr = __fadd_rn(__fmul_rn(__fsub_rn(pc[0], yv), 0.713f), 0.5f);

    yp[tid]  = yv;
    cbp[tid] = cb;
    crp[tid] = cr;
}

// ---------------------------------------------------------------------------
// Kernel B: 5x5 census transform (24 bits, MSB = offset (0,0)), zero border.
// ---------------------------------------------------------------------------
__global__ __launch_bounds__(256) void census_kernel(
    const float* __restrict__ yp, int* __restrict__ cen)
{
    int tid = blockIdx.x * blockDim.x + threadIdx.x;
    if (tid >= 4 * PP) return;
    int p   = tid / PP;
    int rem = tid - p * PP;
    int y   = rem / PW;
    int x   = rem - y * PW;

    int code = 0;
    if (y >= 2 && y < PH - 2 && x >= 2 && x < PW - 2) {
        const float* base = yp + (size_t)p * PP;
        float c = base[y * PW + x];
        int bit = 23;
#pragma unroll
        for (int v = 0; v < 5; ++v) {
#pragma unroll
            for (int u = 0; u < 5; ++u) {
                if (u == 2 && v == 2) continue;  // center excluded
                float nb = base[(y - 2 + v) * PW + (x - 2 + u)];
                code |= (nb >= c ? 1 : 0) << bit;
                --bit;
            }
        }
    }
    cen[tid] = code;
}

// ---------------------------------------------------------------------------
// Kernel C: cost volume + normalization.
// Block = (n, g, row, d-half): stage L/R rows in LDS ONCE, then emit all 64
// disparities for that row from LDS. Global reads ~12MB total.
// Stores are PLAIN float4 (not nontemporal): with LDS staging there is
// nothing left in L2 worth protecting, and the plain-store write-back path
// sustains 6.9 TB/s (measured fill kernel) vs ~4.8 TB/s observed with NT.
// ---------------------------------------------------------------------------
__global__ __launch_bounds__(256) void costvol_kernel(
    const float* __restrict__ cbp, const float* __restrict__ crp,
    const int* __restrict__ cen, float* __restrict__ out)
{
    const float m1 = 11.08282948f, i1 = 1.0f / 0.1949711f;
    const float m2 = 0.02175535f,  i2 = 1.0f / 35.91432953f;
    const float m3 = 0.02679042f,  i3 = 1.0f / 26.79782867f;

    int b   = blockIdx.x;           // 2304 blocks
    int n   = b / 1152;
    int r   = b - n * 1152;
    int g   = r / 384;              // block-uniform
    int r2  = r - g * 384;
    int row = r2 >> 1;
    int dh  = r2 & 1;               // d-half: d = dh*64 + dd

    __shared__ int Ls[776];         // 640 staged + pad for d-overread
    __shared__ int Rs[640];

    const int* Lplane;
    const int* Rplane;
    if (g == 0)      { Lplane = cen + (size_t)n * PP;
                       Rplane = cen + (size_t)(2 + n) * PP; }
    else if (g == 1) { Lplane = (const int*)(cbp + (size_t)n * PP);
                       Rplane = (const int*)(cbp + (size_t)(2 + n) * PP); }
    else             { Lplane = (const int*)(crp + (size_t)n * PP);
                       Rplane = (const int*)(crp + (size_t)(2 + n) * PP); }

    const i32x4* Lg4 = (const i32x4*)(Lplane + row * PW);
    const i32x4* Rg4 = (const i32x4*)(Rplane + row * PW);

    const int t = threadIdx.x;
    for (int j = t; j < 320; j += 256) {
        if (j < 160) *(i32x4*)&Ls[j * 4]         = Lg4[j];
        else         *(i32x4*)&Rs[(j - 160) * 4] = Rg4[j - 160];
    }
    __syncthreads();

    float* outb = out + ((size_t)(n * 384 + g * 128 + dh * 64) * PH + row) * PW;

    if (g == 0) {
        const float c0 = (0.0f - m1) * i1;
#pragma unroll 4
        for (int idx = t; idx < 64 * 160; idx += 256) {
            int dd = idx / 160;            // 0..63
            int q  = idx - dd * 160;
            int x0 = q * 4;
            int d  = dh * 64 + dd;
            int nvalid = PW - d;
            i32x4 rv = *(const i32x4*)&Rs[x0];
            int base = x0 + d;
            int e0 = Ls[base], e1 = Ls[base + 1], e2 = Ls[base + 2], e3 = Ls[base + 3];
            f32x4 ov;
            ov.x = (x0 + 0 < nvalid) ? ((float)__popc(e0 ^ rv.x) - m1) * i1 : c0;
            ov.y = (x0 + 1 < nvalid) ? ((float)__popc(e1 ^ rv.y) - m1) * i1 : c0;
            ov.z = (x0 + 2 < nvalid) ? ((float)__popc(e2 ^ rv.z) - m1) * i1 : c0;
            ov.w = (x0 + 3 < nvalid) ? ((float)__popc(e3 ^ rv.w) - m1) * i1 : c0;
            *(f32x4*)(outb + (size_t)dd * PP + x0) = ov;
        }
    } else {
        const float m  = (g == 1) ? m2 : m3;
        const float iv = (g == 1) ? i2 : i3;
        const float c0 = (0.0f - m) * iv;
        const float* Lf = (const float*)Ls;
        const float* Rf = (const float*)Rs;
#pragma unroll 4
        for (int idx = t; idx < 64 * 160; idx += 256) {
            int dd = idx / 160;
            int q  = idx - dd * 160;
            int x0 = q * 4;
            int d  = dh * 64 + dd;
            int nvalid = PW - d;
            f32x4 rv = *(const f32x4*)&Rf[x0];
            int base = x0 + d;
            float e0 = Lf[base], e1 = Lf[base + 1], e2 = Lf[base + 2], e3 = Lf[base + 3];
            f32x4 ov;
            ov.x = (x0 + 0 < nvalid) ? (fabsf(e0 - rv.x) - m) * iv : c0;
            ov.y = (x0 + 1 < nvalid) ? (fabsf(e1 - rv.y) - m) * iv : c0;
            ov.z = (x0 + 2 < nvalid) ? (fabsf(e2 - rv.z) - m) * iv : c0;
            ov.w = (x0 + 3 < nvalid) ? (fabsf(e3 - rv.w) - m) * iv : c0;
            *(f32x4*)(outb + (size_t)dd * PP + x0) = ov;
        }
    }
}

// ---------------------------------------------------------------------------
extern "C" void kernel_launch(void* const* d_in, const int* in_sizes, int n_in,
                              void* d_out, int out_size, void* d_ws, size_t ws_size,
                              hipStream_t stream)
{
    const float* left  = (const float*)d_in[0];
    const float* right = (const float*)d_in[1];

    float* ws  = (float*)d_ws;
    float* yp  = ws;                     // 4 planes of PP floats
    float* cbp = ws + 4 * PP;
    float* crp = ws + 8 * PP;
    int*   cen = (int*)(ws + 12 * PP);   // 4 planes of PP int32

    int threads = 256;
    int blocksAB = (4 * PP + threads - 1) / threads;   // 1920

    pool_ycbcr_kernel<<<blocksAB, threads, 0, stream>>>(left, right, yp, cbp, crp);
    census_kernel<<<blocksAB, threads, 0, stream>>>(yp, cen);

    int blocksC = 2 * 3 * 192 * 2;   // 2304: (n, g, row, d-half)
    costvol_kernel<<<blocksC, threads, 0, stream>>>(cbp, crp, cen, (float*)d_out);
}